// Round 4
// baseline (14809.268 us; speedup 1.0000x reference)
//
#include <hip/hip_runtime.h>
#include <hip/hip_bf16.h>

typedef __attribute__((ext_vector_type(8))) short short8;
typedef __attribute__((ext_vector_type(4))) float float4v;

__device__ __forceinline__ float bf2f(short b) {
    unsigned u = ((unsigned)(unsigned short)b) << 16;
    union { unsigned u; float f; } c; c.u = u; return c.f;
}
__device__ __forceinline__ short f2bf(float f) {
    union { float f; unsigned u; } c; c.f = f;
    unsigned r = 0x7FFFu + ((c.u >> 16) & 1u);
    return (short)((c.u + r) >> 16);
}
// dtype-dispatched scalar load (flag: false=bf16, true=fp32)
__device__ __forceinline__ float ldf(const void* p, size_t i, bool f32) {
    return f32 ? ((const float*)p)[i] : bf2f(((const short*)p)[i]);
}
// dtype-dispatched 8-element MFMA fragment load (rounds fp32 -> bf16)
__device__ __forceinline__ short8 frag8(const void* p, size_t i, bool f32) {
    short8 r;
    if (f32) {
        const float* q = (const float*)p + i;
#pragma unroll
        for (int j = 0; j < 8; j++) r[j] = f2bf(q[j]);
    } else {
        r = *(const short8*)((const short*)p + i);
    }
    return r;
}

// ---------------- dtype detector: 0 = bf16, 1 = fp32 ----------------
__global__ void detect_dtype(const unsigned short* __restrict__ in, unsigned* __restrict__ flag)
{
    int t = threadIdx.x;  // 64 threads
    int sane = 0;
    for (int i = t; i < 256; i += 64) {
        unsigned e = (in[i] >> 7) & 0xFF;
        sane += (e >= 0x70 && e <= 0x8A) ? 1 : 0;
    }
#pragma unroll
    for (int o = 32; o > 0; o >>= 1) sane += __shfl_down(sane, o);
    if (t == 0) *flag = (sane >= 200) ? 0u : 1u;
}

// ---------------- init scratch (h ping-pong hi/lo planes + flags) ----------------
__global__ void init_scratch(short* __restrict__ hb, unsigned* __restrict__ cnt)
{
    int i = blockIdx.x * 256 + threadIdx.x;
    if (i < 4 * 65536) hb[i] = 0;
    if (i < 512) cnt[i] = 0;
}

// ---------------- C = A @ B^T + bias, bf16 MFMA, optional fp32 hi/lo split --------
__global__ __launch_bounds__(256, 1) void gemm_bt(
    const void* __restrict__ A, const void* __restrict__ B,
    const void* __restrict__ bias, void* __restrict__ outbase, size_t coff,
    const unsigned* __restrict__ flag, int M, int N, int K)
{
    const bool f32 = flag && (flag[0] != 0u);
    __shared__ short Ah[128][72], Bh[128][72];
    __shared__ short Al[128][72], Bl[128][72];
    const int tid  = threadIdx.x;
    const int wid  = tid >> 6;
    const int lane = tid & 63;
    const int ln = lane & 15, q = lane >> 4;
    const int bm = blockIdx.x * 128, bn = blockIdx.y * 128;
    const int wm = (wid & 1) * 64, wn = (wid >> 1) * 64;

    float4v acc[4][4];
#pragma unroll
    for (int i = 0; i < 4; i++)
#pragma unroll
        for (int j = 0; j < 4; j++) acc[i][j] = (float4v){0.f, 0.f, 0.f, 0.f};

    for (int k0 = 0; k0 < K; k0 += 64) {
#pragma unroll
        for (int c = 0; c < 4; c++) {
            int chunk = tid + c * 256;
            int row = chunk >> 3;
            int kq  = (chunk & 7) * 8;
            size_t ga = (size_t)(bm + row) * K + k0 + kq;
            size_t gb = (size_t)(bn + row) * K + k0 + kq;
            if (f32) {
                const float* Af = (const float*)A;
                const float* Bf = (const float*)B;
#pragma unroll
                for (int j = 0; j < 8; j++) {
                    float av = Af[ga + j], bv = Bf[gb + j];
                    short ah = f2bf(av), bh = f2bf(bv);
                    Ah[row][kq + j] = ah; Al[row][kq + j] = f2bf(av - bf2f(ah));
                    Bh[row][kq + j] = bh; Bl[row][kq + j] = f2bf(bv - bf2f(bh));
                }
            } else {
                *(short8*)&Ah[row][kq] = *(const short8*)((const short*)A + ga);
                *(short8*)&Bh[row][kq] = *(const short8*)((const short*)B + gb);
            }
        }
        __syncthreads();
#pragma unroll
        for (int kt = 0; kt < 2; kt++) {
            short8 avh[4], bvh[4];
#pragma unroll
            for (int i = 0; i < 4; i++) avh[i] = *(const short8*)&Ah[wm + i * 16 + ln][kt * 32 + q * 8];
#pragma unroll
            for (int j = 0; j < 4; j++) bvh[j] = *(const short8*)&Bh[wn + j * 16 + ln][kt * 32 + q * 8];
#pragma unroll
            for (int i = 0; i < 4; i++)
#pragma unroll
                for (int j = 0; j < 4; j++)
                    acc[i][j] = __builtin_amdgcn_mfma_f32_16x16x32_bf16(avh[i], bvh[j], acc[i][j], 0, 0, 0);
            if (f32) {
                short8 avl[4], bvl[4];
#pragma unroll
                for (int i = 0; i < 4; i++) avl[i] = *(const short8*)&Al[wm + i * 16 + ln][kt * 32 + q * 8];
#pragma unroll
                for (int j = 0; j < 4; j++) bvl[j] = *(const short8*)&Bl[wn + j * 16 + ln][kt * 32 + q * 8];
#pragma unroll
                for (int i = 0; i < 4; i++)
#pragma unroll
                    for (int j = 0; j < 4; j++) {
                        acc[i][j] = __builtin_amdgcn_mfma_f32_16x16x32_bf16(avh[i], bvl[j], acc[i][j], 0, 0, 0);
                        acc[i][j] = __builtin_amdgcn_mfma_f32_16x16x32_bf16(avl[i], bvh[j], acc[i][j], 0, 0, 0);
                    }
            }
        }
        __syncthreads();
    }
    // C/D layout: col = lane&15, row = (lane>>4)*4 + reg
#pragma unroll
    for (int j = 0; j < 4; j++) {
        int col = bn + wn + j * 16 + ln;
        float bvv = ldf(bias, col, f32);
#pragma unroll
        for (int i = 0; i < 4; i++) {
#pragma unroll
            for (int r = 0; r < 4; r++) {
                int row = bm + wm + i * 16 + q * 4 + r;
                size_t idx = coff + (size_t)row * N + col;
                float v = acc[i][j][r] + bvv;
                if (f32) ((float*)outbase)[idx] = v;
                else     ((short*)outbase)[idx] = f2bf(v);
            }
        }
    }
}

// ---------------- persistent GRU recurrence (FENCE-FREE, L2-bypass h exchange) ----
// All inter-WG-shared state (h planes, flags) moves through agent-scope RELAXED
// atomics (sc1 -> bypass L2, coherent at Infinity Cache). No buffer_wbl2, no
// buffer_inv anywhere: producers drain sc1 stores with s_waitcnt vmcnt(0) +
// barrier before the relaxed flag store; consumers poll relaxed then barrier.
// h staged to LDS via register staging (u64 atomic loads -> ds_write_b128) in
// 8 x 32KB chunks, double-buffered: issue loads for chunk k+1, MFMA chunk k,
// write k+1, barrier. x_t (read-only, plain loads, L2-cacheable) staged before
// the poll to absorb producer skew; x-MFMA covers chunk-0 load latency.
#define NWG 64
__global__ __launch_bounds__(192, 1) void gru_rec(
    const void* __restrict__ inputs,   // (64,512,512)
    const void* __restrict__ Wx,       // (3072,512)
    const void* __restrict__ bx,       // 3072
    const void* __restrict__ Wh,       // (3072,1024)
    const void* __restrict__ bh,       // 3072
    short* __restrict__ hb,            // 4 planes of 65536 bf16 (ping hi/lo, pong hi/lo)
    unsigned* __restrict__ cnt,        // 512 u32: flags[2][64] padded x4 (zeroed)
    const unsigned* __restrict__ flag, // dtype flag (may be null -> bf16)
    void* __restrict__ hid)            // (64,512,1024) output 0
{
    const bool f32 = flag && (flag[0] != 0u);
    __shared__ short sbuf[4][16384];   // 4 x 32KB; x uses [0..1]; h chunk k -> sbuf[(2+k)&3]
    __shared__ float Px[3][64][17];
    __shared__ float Ph[3][64][17];
    __shared__ float hown[64][17];
    __shared__ float bxs[3][16], bhs[3][16];

    const int tid  = threadIdx.x;
    const int w    = blockIdx.x;
    const int g    = tid >> 6;         // 0..2 (gate / wave)
    const int lane = tid & 63;
    const int ln   = lane & 15, q = lane >> 4;

    // Wh / Wx B-fragments in registers: B[k][n]: n=lane&15, k=(lane>>4)*8+j
    const size_t whbase = (size_t)(g * 1024 + w * 16 + ln) * 1024;
    short8 wf[32];
#pragma unroll
    for (int kt = 0; kt < 32; kt++) wf[kt] = frag8(Wh, whbase + kt * 32 + q * 8, f32);

    const size_t wxbase = (size_t)(g * 1024 + w * 16 + ln) * 512;
    short8 wxf[16];
#pragma unroll
    for (int kt = 0; kt < 16; kt++) wxf[kt] = frag8(Wx, wxbase + kt * 32 + q * 8, f32);

    for (int e = tid; e < 1024; e += 192) hown[e >> 4][e & 15] = 0.f;
    if (tid < 48) {
        int gg = tid >> 4, jj = tid & 15;
        bxs[gg][jj] = ldf(bx, gg * 1024 + w * 16 + jj, f32);
        bhs[gg][jj] = ldf(bh, gg * 1024 + w * 16 + jj, f32);
    }
    __syncthreads();

    for (int t = 0; t < 512; t++) {
        const short* hsrc = hb + (size_t)((t & 1) ? 2 : 0) * 65536;
        short*       hdst = hb + (size_t)((t & 1) ? 0 : 2) * 65536;

        float4v ax[4], ah[4];
#pragma unroll
        for (int mt = 0; mt < 4; mt++) { ax[mt] = (float4v){0.f,0.f,0.f,0.f}; ah[mt] = (float4v){0.f,0.f,0.f,0.f}; }

        // per-chunk register staging: 11 rows x 16B per wave (u64 x2, sc1 loads)
        unsigned long long rv[11][2];
        auto load_chunk = [&](int k2) {
            const short* src_ = hsrc + (k2 >> 2) * 65536 + (k2 & 3) * 16384;
#pragma unroll
            for (int r = 0; r < 11; r++) { int s = g + 3 * r; if (s < 32) {
                const unsigned long long* p_ = (const unsigned long long*)(src_ + s * 512 + (size_t)lane * 8);
                rv[r][0] = __hip_atomic_load(p_,     __ATOMIC_RELAXED, __HIP_MEMORY_SCOPE_AGENT);
                rv[r][1] = __hip_atomic_load(p_ + 1, __ATOMIC_RELAXED, __HIP_MEMORY_SCOPE_AGENT);
            } }
        };
        auto write_chunk = [&](int k2) {
            short* dst_ = &sbuf[(2 + k2) & 3][0];
#pragma unroll
            for (int r = 0; r < 11; r++) { int s = g + 3 * r; if (s < 32) {
                union { unsigned long long qq[2]; short8 v; } u_;
                u_.qq[0] = rv[r][0]; u_.qq[1] = rv[r][1];
                *(short8*)&dst_[s * 512 + lane * 8] = u_.v;
            } }
        };

        // ===== stage x_t -> sbuf[0..1]; layout [kb=lane][b]: byte kb*1024 + (b*16 ^ ((kb&7)<<4))
        // (XOR swizzle: conflict-free ds_write AND conflict-free frag ds_read).
        // Reads only `inputs` (read-only, plain/L2-cached) -> legal before the
        // barrier; absorbs producer skew.
#pragma unroll 8
        for (int r = 0; r < 22; r++) {
            int b = g + 3 * r;
            if (b < 64) {
                size_t gi = (size_t)b * 262144 + (size_t)t * 512 + (size_t)lane * 8;
                short8 v = frag8(inputs, gi, f32);
                *(short8*)((char*)&sbuf[0][0] + lane * 1024 + ((b * 16) ^ ((lane & 7) << 4))) = v;
            }
        }
        __syncthreads();

        // ===== resolve producer flags for h(t-1): 64-lane parallel relaxed poll.
        // NO acquire fence: all h reads below are sc1 (L2-bypass) -> no stale copy.
        if (t) {
            if (tid < 64) {
                const unsigned* fp = &cnt[(((t - 1) & 1) * 64 + tid) * 4];
                while (__hip_atomic_load(fp, __ATOMIC_RELAXED, __HIP_MEMORY_SCOPE_AGENT) < (unsigned)t)
                    __builtin_amdgcn_s_sleep(2);
            }
            __syncthreads();
        }

        // ===== prologue: issue chunk-0 loads; x-MFMA covers their latency
        load_chunk(0);
#pragma unroll
        for (int ktl = 0; ktl < 16; ktl++) {
            const int kb = ktl * 4 + q;
#pragma unroll
            for (int mt = 0; mt < 4; mt++) {
                short8 a = *(const short8*)((const char*)&sbuf[0][0] +
                               kb * 1024 + (((mt * 16 + ln) * 16) ^ ((kb & 7) << 4)));
                ax[mt] = __builtin_amdgcn_mfma_f32_16x16x32_bf16(a, wxf[ktl], ax[mt], 0, 0, 0);
            }
        }
        write_chunk(0);
        __syncthreads();

        // ===== h phase: 8 chunks of 32KB, software-pipelined
#pragma unroll
        for (int k2 = 0; k2 < 8; k2++) {
            if (k2 < 7) load_chunk(k2 + 1);
            {
                const short* bb = &sbuf[(2 + k2) & 3][0];
#pragma unroll
                for (int ktl = 0; ktl < 8; ktl++) {
                    const int kb = ktl * 4 + q;
#pragma unroll
                    for (int mt = 0; mt < 4; mt++) {
                        short8 a = *(const short8*)&bb[kb * 512 + (mt * 16 + ln) * 8];
                        ah[mt] = __builtin_amdgcn_mfma_f32_16x16x32_bf16(a, wf[(k2 & 3) * 8 + ktl], ah[mt], 0, 0, 0);
                    }
                }
            }
            if (k2 < 7) { write_chunk(k2 + 1); __syncthreads(); }
        }

        // ===== accumulators -> LDS (C/D: col = lane&15, row = (lane>>4)*4 + reg)
#pragma unroll
        for (int mt = 0; mt < 4; mt++)
#pragma unroll
            for (int r = 0; r < 4; r++) {
                int row = mt * 16 + q * 4 + r;
                Px[g][row][ln] = ax[mt][r];
                Ph[g][row][ln] = ah[mt][r];
            }
        __syncthreads();

        // ===== gates + h update
        for (int e = tid; e < 1024; e += 192) {
            int b = e >> 4, jj = e & 15;
            float xr = Px[0][b][jj] + bxs[0][jj];
            float xu = Px[1][b][jj] + bxs[1][jj];
            float xn = Px[2][b][jj] + bxs[2][jj];
            float pr = Ph[0][b][jj] + bhs[0][jj];
            float pu = Ph[1][b][jj] + bhs[1][jj];
            float pn = Ph[2][b][jj] + bhs[2][jj];
            float rg = 1.f / (1.f + __expf(-(xr + pr)));
            float ug = 1.f / (1.f + __expf(-(xu + pu)));
            float ng = tanhf(xn + rg * pn);
            float hy = ug * hown[b][jj] + (1.f - ug) * ng;
            hown[b][jj] = hy;
            size_t hidx = ((size_t)b * 512 + t) * 1024 + w * 16 + jj;
            if (f32) ((float*)hid)[hidx] = hy;
            else     ((short*)hid)[hidx] = f2bf(hy);
        }
        __syncthreads();

        // ===== h out: blocked [kb][b][8], hi + lo planes, sc1 write-through
        // (agent relaxed atomic u64 stores: no dirty L2 lines -> no wbl2 needed)
        for (int e = tid; e < 256; e += 192) {
            int b = e & 63, kbl = (e >> 6) & 1, pl = e >> 7;
            union { unsigned long long qq[2]; short8 v; } u;
#pragma unroll
            for (int j = 0; j < 8; j++) {
                float hy = hown[b][kbl * 8 + j];
                short hh = f2bf(hy);
                u.v[j] = pl ? f2bf(hy - bf2f(hh)) : hh;
            }
            unsigned long long* dp = (unsigned long long*)
                &hdst[(size_t)pl * 65536 + (size_t)(w * 2 + kbl) * 512 + b * 8];
            __hip_atomic_store(dp,     u.qq[0], __ATOMIC_RELAXED, __HIP_MEMORY_SCOPE_AGENT);
            __hip_atomic_store(dp + 1, u.qq[1], __ATOMIC_RELAXED, __HIP_MEMORY_SCOPE_AGENT);
        }
        // sc1 stores are IC-visible once vmcnt retires: drain, then barrier, then flag.
        asm volatile("s_waitcnt vmcnt(0)" ::: "memory");
        __syncthreads();

        // ===== arrive: relaxed store to OWN padded flag slot (no fence)
        if (tid == 0)
            __hip_atomic_store(&cnt[((t & 1) * 64 + w) * 4], (unsigned)(t + 1),
                               __ATOMIC_RELAXED, __HIP_MEMORY_SCOPE_AGENT);
    }
}

extern "C" void kernel_launch(void* const* d_in, const int* in_sizes, int n_in,
                              void* d_out, int out_size, void* d_ws, size_t ws_size,
                              hipStream_t stream)
{
    const void* inputs = d_in[0];
    const void* Wx     = d_in[1];
    const void* bx     = d_in[2];
    const void* Wh     = d_in[3];
    const void* bh     = d_in[4];
    const void* Wo     = d_in[5];
    const void* bo     = d_in[6];

    const size_t HID_ELEMS = (size_t)64 * 512 * 1024;   // 33,554,432

    short* hb; unsigned* cnt; unsigned* flag;
    const bool use_ws = (d_ws != nullptr) && (ws_size >= (size_t)(4096 + 4 * 65536 * 2));
    if (use_ws) {
        cnt  = (unsigned*)d_ws;                  // 512 u32: flags[2][64] x4 pad
        flag = cnt + 512;                        // 1 u32
        hb   = (short*)((char*)d_ws + 4096);     // 512 KiB, 16B-aligned
    } else {
        short* outh = (short*)d_out + HID_ELEMS;
        hb   = outh;
        cnt  = (unsigned*)(outh + 4 * 65536);
        flag = nullptr;
    }

    if (use_ws) detect_dtype<<<1, 64, 0, stream>>>((const unsigned short*)inputs, flag);
    init_scratch<<<1024, 256, 0, stream>>>(hb, cnt);
    gru_rec<<<NWG, 192, 0, stream>>>(inputs, Wx, bx, Wh, bh, hb, cnt, flag, d_out);
    // out = hiddens @ Wo^T + bo : (32768 x 1024) @ (1024 x 512)
    gemm_bt<<<dim3(256, 4), 256, 0, stream>>>(d_out, Wo, bo, d_out, HID_ELEMS, flag, 32768, 512, 1024);
}

// Round 8
// 5791.108 us; speedup vs baseline: 2.5572x; 2.5572x over previous
//
#include <hip/hip_runtime.h>
#include <hip/hip_bf16.h>

typedef __attribute__((ext_vector_type(8))) short short8;
typedef __attribute__((ext_vector_type(4))) float float4v;

__device__ __forceinline__ float bf2f(short b) {
    unsigned u = ((unsigned)(unsigned short)b) << 16;
    union { unsigned u; float f; } c; c.u = u; return c.f;
}
__device__ __forceinline__ short f2bf(float f) {
    union { float f; unsigned u; } c; c.f = f;
    unsigned r = 0x7FFFu + ((c.u >> 16) & 1u);
    return (short)((c.u + r) >> 16);
}
// dtype-dispatched scalar load (flag: false=bf16, true=fp32)
__device__ __forceinline__ float ldf(const void* p, size_t i, bool f32) {
    return f32 ? ((const float*)p)[i] : bf2f(((const short*)p)[i]);
}
// dtype-dispatched 8-element MFMA fragment load (rounds fp32 -> bf16)
__device__ __forceinline__ short8 frag8(const void* p, size_t i, bool f32) {
    short8 r;
    if (f32) {
        const float* q = (const float*)p + i;
#pragma unroll
        for (int j = 0; j < 8; j++) r[j] = f2bf(q[j]);
    } else {
        r = *(const short8*)((const short*)p + i);
    }
    return r;
}

// ---------------- calibrated clock meter ----------------
// Issue-bound dependent-FMA chain, 8 waves/SIMD, full grid: SIMD issue cycles
// = 8 waves * iters*16 fma * 2 cy  ->  iters=7032 => ~750 us @2.4 GHz.
// Runs AFTER gru_rec; its duration (inferred from total) reads the shader clock
// the governor settled to during the recurrence.
__global__ __launch_bounds__(256) void dpm_spin(const float* __restrict__ seed,
                                               float* __restrict__ sink, int iters)
{
    float a = seed[threadIdx.x & 15];
    float b = seed[(threadIdx.x & 15) + 16];
    a = (a > 2.f || a < -2.f || (a < 0.01f && a > -0.01f)) ? 1.0000001f : a;
    float x = b + 1.f;
    int n = iters * 16;
#pragma unroll 16
    for (int i = 0; i < n; i++) x = __builtin_fmaf(x, a, b);
    if (x == 12345.6789f) sink[(((size_t)blockIdx.x * 256 + threadIdx.x) & 65535)] = x;
}

// ---------------- dtype detector: 0 = bf16, 1 = fp32 ----------------
__global__ void detect_dtype(const unsigned short* __restrict__ in, unsigned* __restrict__ flag)
{
    int t = threadIdx.x;  // 64 threads
    int sane = 0;
    for (int i = t; i < 256; i += 64) {
        unsigned e = (in[i] >> 7) & 0xFF;
        sane += (e >= 0x70 && e <= 0x8A) ? 1 : 0;
    }
#pragma unroll
    for (int o = 32; o > 0; o >>= 1) sane += __shfl_down(sane, o);
    if (t == 0) *flag = (sane >= 200) ? 0u : 1u;
}

// ---------------- init scratch (h ping-pong hi/lo planes + flags) ----------------
__global__ void init_scratch(short* __restrict__ hb, unsigned* __restrict__ cnt)
{
    int i = blockIdx.x * 256 + threadIdx.x;
    if (i < 4 * 65536) hb[i] = 0;
    if (i < 512) cnt[i] = 0;
}

// ---------------- C = A @ B^T + bias, bf16 MFMA, optional fp32 hi/lo split --------
__global__ __launch_bounds__(256, 1) void gemm_bt(
    const void* __restrict__ A, const void* __restrict__ B,
    const void* __restrict__ bias, void* __restrict__ outbase, size_t coff,
    const unsigned* __restrict__ flag, int M, int N, int K)
{
    const bool f32 = flag && (flag[0] != 0u);
    __shared__ short Ah[128][72], Bh[128][72];
    __shared__ short Al[128][72], Bl[128][72];
    const int tid  = threadIdx.x;
    const int wid  = tid >> 6;
    const int lane = tid & 63;
    const int ln = lane & 15, q = lane >> 4;
    const int bm = blockIdx.x * 128, bn = blockIdx.y * 128;
    const int wm = (wid & 1) * 64, wn = (wid >> 1) * 64;

    float4v acc[4][4];
#pragma unroll
    for (int i = 0; i < 4; i++)
#pragma unroll
        for (int j = 0; j < 4; j++) acc[i][j] = (float4v){0.f, 0.f, 0.f, 0.f};

    for (int k0 = 0; k0 < K; k0 += 64) {
#pragma unroll
        for (int c = 0; c < 4; c++) {
            int chunk = tid + c * 256;
            int row = chunk >> 3;
            int kq  = (chunk & 7) * 8;
            size_t ga = (size_t)(bm + row) * K + k0 + kq;
            size_t gb = (size_t)(bn + row) * K + k0 + kq;
            if (f32) {
                const float* Af = (const float*)A;
                const float* Bf = (const float*)B;
#pragma unroll
                for (int j = 0; j < 8; j++) {
                    float av = Af[ga + j], bv = Bf[gb + j];
                    short ah = f2bf(av), bh = f2bf(bv);
                    Ah[row][kq + j] = ah; Al[row][kq + j] = f2bf(av - bf2f(ah));
                    Bh[row][kq + j] = bh; Bl[row][kq + j] = f2bf(bv - bf2f(bh));
                }
            } else {
                *(short8*)&Ah[row][kq] = *(const short8*)((const short*)A + ga);
                *(short8*)&Bh[row][kq] = *(const short8*)((const short*)B + gb);
            }
        }
        __syncthreads();
#pragma unroll
        for (int kt = 0; kt < 2; kt++) {
            short8 avh[4], bvh[4];
#pragma unroll
            for (int i = 0; i < 4; i++) avh[i] = *(const short8*)&Ah[wm + i * 16 + ln][kt * 32 + q * 8];
#pragma unroll
            for (int j = 0; j < 4; j++) bvh[j] = *(const short8*)&Bh[wn + j * 16 + ln][kt * 32 + q * 8];
#pragma unroll
            for (int i = 0; i < 4; i++)
#pragma unroll
                for (int j = 0; j < 4; j++)
                    acc[i][j] = __builtin_amdgcn_mfma_f32_16x16x32_bf16(avh[i], bvh[j], acc[i][j], 0, 0, 0);
            if (f32) {
                short8 avl[4], bvl[4];
#pragma unroll
                for (int i = 0; i < 4; i++) avl[i] = *(const short8*)&Al[wm + i * 16 + ln][kt * 32 + q * 8];
#pragma unroll
                for (int j = 0; j < 4; j++) bvl[j] = *(const short8*)&Bl[wn + j * 16 + ln][kt * 32 + q * 8];
#pragma unroll
                for (int i = 0; i < 4; i++)
#pragma unroll
                    for (int j = 0; j < 4; j++) {
                        acc[i][j] = __builtin_amdgcn_mfma_f32_16x16x32_bf16(avh[i], bvl[j], acc[i][j], 0, 0, 0);
                        acc[i][j] = __builtin_amdgcn_mfma_f32_16x16x32_bf16(avl[i], bvh[j], acc[i][j], 0, 0, 0);
                    }
            }
        }
        __syncthreads();
    }
    // C/D layout: col = lane&15, row = (lane>>4)*4 + reg
#pragma unroll
    for (int j = 0; j < 4; j++) {
        int col = bn + wn + j * 16 + ln;
        float bvv = ldf(bias, col, f32);
#pragma unroll
        for (int i = 0; i < 4; i++) {
#pragma unroll
            for (int r = 0; r < 4; r++) {
                int row = bm + wm + i * 16 + q * 4 + r;
                size_t idx = coff + (size_t)row * N + col;
                float v = acc[i][j][r] + bvv;
                if (f32) ((float*)outbase)[idx] = v;
                else     ((short*)outbase)[idx] = f2bf(v);
            }
        }
    }
}

// ---------------- persistent GRU recurrence, GROUP-LOCAL sync ------------------
// KEY: batch rows are independent recurrences. Partition batch into 4 groups of
// 16 rows; each group has its own 64 column-WGs (grid 256 = all CUs). Sync and
// h-exchange are group-local: per step a WG reads only its group's h (64 KB:
// hi+lo planes of 16 rows) and polls only its group's 64 flags. M=16 MFMA tile.
// h planes (global, sc1/IC-coherent): plane[group][kb=128][r=16][8] shorts;
// LDS chunks [kb][r^(kb&15)][8] (r-slot XOR swizzle: conflict-free frag reads).
// Coherence unchanged from R4: relaxed sc1 loads/stores, zero fences,
// vmcnt(0)+barrier before the per-WG flag store.
#define NWG 256
__global__ __launch_bounds__(192, 1) void gru_rec(
    const void* __restrict__ inputs,   // (64,512,512)
    const void* __restrict__ Wx,       // (3072,512)
    const void* __restrict__ bx,       // 3072
    const void* __restrict__ Wh,       // (3072,1024)
    const void* __restrict__ bh,       // 3072
    short* __restrict__ hb,            // 4 planes of 65536 bf16 (ping hi/lo, pong hi/lo)
    unsigned* __restrict__ cnt,        // 512 u32: flags[2][4][64] (zeroed)
    const unsigned* __restrict__ flag, // dtype flag (may be null -> bf16)
    void* __restrict__ hid)            // (64,512,1024) output 0
{
    const bool f32 = flag && (flag[0] != 0u);
    __shared__ short xs[8192];         // x tile 16 KB: [kb=64][r=16][8], r-swizzled
    __shared__ short hs[2][16384];     // h chunk dbuf 2x32 KB: [kb=128][r=16][8], r-swizzled
    __shared__ float Px[3][16][17];
    __shared__ float Ph[3][16][17];
    __shared__ float hown[16][17];
    __shared__ float bxs[3][16], bhs[3][16];

    const int tid  = threadIdx.x;
    const int w    = blockIdx.x;
    const int gb   = w >> 6;           // batch group 0..3 (rows gb*16 .. gb*16+15)
    const int c    = w & 63;           // column WG (H cols c*16 .. c*16+15 per gate)
    const int g    = tid >> 6;         // 0..2 (gate / wave)
    const int lane = tid & 63;
    const int ln   = lane & 15, q = lane >> 4;

    // Wh / Wx B-fragments in registers: B[k][n]: n=lane&15, k=(lane>>4)*8+j
    const size_t whbase = (size_t)(g * 1024 + c * 16 + ln) * 1024;
    short8 wf[32];
#pragma unroll
    for (int kt = 0; kt < 32; kt++) wf[kt] = frag8(Wh, whbase + kt * 32 + q * 8, f32);

    const size_t wxbase = (size_t)(g * 1024 + c * 16 + ln) * 512;
    short8 wxf[16];
#pragma unroll
    for (int kt = 0; kt < 16; kt++) wxf[kt] = frag8(Wx, wxbase + kt * 32 + q * 8, f32);

    for (int e = tid; e < 256; e += 192) hown[e >> 4][e & 15] = 0.f;
    if (tid < 48) {
        int gg = tid >> 4, jj = tid & 15;
        bxs[gg][jj] = ldf(bx, gg * 1024 + c * 16 + jj, f32);
        bhs[gg][jj] = ldf(bh, gg * 1024 + c * 16 + jj, f32);
    }
    __syncthreads();

    for (int t = 0; t < 512; t++) {
        // group-local plane bases (hi at +0, lo at +65536 within the phase pair)
        const short* hsrc = hb + (size_t)((t & 1) ? 2 : 0) * 65536 + gb * 16384;
        short*       hdst = hb + (size_t)((t & 1) ? 0 : 2) * 65536 + gb * 16384;

        float4v ax = (float4v){0.f,0.f,0.f,0.f};
        float4v ah = (float4v){0.f,0.f,0.f,0.f};

        // per-chunk register staging: 32 KB / 192 threads = 11 x 16B (u64 x2, sc1)
        unsigned long long rv[11][2];
        auto load_chunk = [&](int pl) {   // pl: 0=hi plane, 1=lo plane
            const short* src_ = hsrc + pl * 65536;
#pragma unroll
            for (int i = 0; i < 11; i++) { int e = tid + i * 192; if (e < 2048) {
                const unsigned long long* p_ = (const unsigned long long*)(src_ + e * 8);
                rv[i][0] = __hip_atomic_load(p_,     __ATOMIC_RELAXED, __HIP_MEMORY_SCOPE_AGENT);
                rv[i][1] = __hip_atomic_load(p_ + 1, __ATOMIC_RELAXED, __HIP_MEMORY_SCOPE_AGENT);
            } }
        };
        auto write_chunk = [&](int d) {   // d: LDS dbuf index
#pragma unroll
            for (int i = 0; i < 11; i++) { int e = tid + i * 192; if (e < 2048) {
                int kb = e >> 4, r = e & 15;
                union { unsigned long long qq[2]; short8 v; } u_;
                u_.qq[0] = rv[i][0]; u_.qq[1] = rv[i][1];
                *(short8*)((char*)&hs[d][0] + (kb << 8) + ((r ^ (kb & 15)) << 4)) = u_.v;
            } }
        };

        // ===== stage x_t (16 rows x 512) -> xs; coalesced 1KB rows, r-swizzled LDS
#pragma unroll 4
        for (int i = 0; i < 6; i++) { int e = tid + i * 192; if (e < 1024) {
            int kb = e & 63, r = e >> 6;
            size_t gi = (size_t)(gb * 16 + r) * 262144 + (size_t)t * 512 + kb * 8;
            short8 v = frag8(inputs, gi, f32);
            *(short8*)((char*)xs + (kb << 8) + ((r ^ (kb & 15)) << 4)) = v;
        } }
        __syncthreads();

        // ===== resolve OWN GROUP's 64 producer flags (relaxed parallel poll)
        if (t) {
            if (tid < 64) {
                const unsigned* fp = &cnt[((t - 1) & 1) * 256 + gb * 64 + tid];
                while (__hip_atomic_load(fp, __ATOMIC_RELAXED, __HIP_MEMORY_SCOPE_AGENT) < (unsigned)t)
                    __builtin_amdgcn_s_sleep(2);
            }
            __syncthreads();
        }

        // ===== prologue: issue hi-plane loads; x-MFMA covers their latency
        load_chunk(0);
#pragma unroll
        for (int kt = 0; kt < 16; kt++) {
            int kb = kt * 4 + q;
            short8 a = *(const short8*)((const char*)xs + (kb << 8) + ((ln ^ (kb & 15)) << 4));
            ax = __builtin_amdgcn_mfma_f32_16x16x32_bf16(a, wxf[kt], ax, 0, 0, 0);
        }
        write_chunk(0);
        __syncthreads();

        // ===== lo-plane loads in flight while hi-plane MFMA runs
        load_chunk(1);
#pragma unroll
        for (int kt = 0; kt < 32; kt++) {
            int kb = kt * 4 + q;
            short8 a = *(const short8*)((const char*)&hs[0][0] + (kb << 8) + ((ln ^ (kb & 15)) << 4));
            ah = __builtin_amdgcn_mfma_f32_16x16x32_bf16(a, wf[kt], ah, 0, 0, 0);
        }
        write_chunk(1);
        __syncthreads();
#pragma unroll
        for (int kt = 0; kt < 32; kt++) {
            int kb = kt * 4 + q;
            short8 a = *(const short8*)((const char*)&hs[1][0] + (kb << 8) + ((ln ^ (kb & 15)) << 4));
            ah = __builtin_amdgcn_mfma_f32_16x16x32_bf16(a, wf[kt], ah, 0, 0, 0);
        }

        // ===== accumulators -> LDS (C/D: col = lane&15, row = (lane>>4)*4 + reg)
#pragma unroll
        for (int r = 0; r < 4; r++) {
            Px[g][q * 4 + r][ln] = ax[r];
            Ph[g][q * 4 + r][ln] = ah[r];
        }
        __syncthreads();

        // ===== gates + h update (16 rows x 16 cols per WG)
        for (int e = tid; e < 256; e += 192) {
            int r = e >> 4, jj = e & 15;
            float xr = Px[0][r][jj] + bxs[0][jj];
            float xu = Px[1][r][jj] + bxs[1][jj];
            float xn = Px[2][r][jj] + bxs[2][jj];
            float pr = Ph[0][r][jj] + bhs[0][jj];
            float pu = Ph[1][r][jj] + bhs[1][jj];
            float pn = Ph[2][r][jj] + bhs[2][jj];
            float rg = 1.f / (1.f + __expf(-(xr + pr)));
            float ug = 1.f / (1.f + __expf(-(xu + pu)));
            float ng = tanhf(xn + rg * pn);
            float hy = ug * hown[r][jj] + (1.f - ug) * ng;
            hown[r][jj] = hy;
            size_t b = (size_t)(gb * 16 + r);
            size_t hidx = (b * 512 + t) * 1024 + c * 16 + jj;
            if (f32) ((float*)hid)[hidx] = hy;
            else     ((short*)hid)[hidx] = f2bf(hy);
        }
        __syncthreads();

        // ===== h out: own 16 cols (kb = 2c, 2c+1), hi+lo planes, sc1 16B stores
        if (tid < 64) {
            int r = tid & 15, kbl = (tid >> 4) & 1, pl = (tid >> 5) & 1;
            union { unsigned long long qq[2]; short8 v; } u;
#pragma unroll
            for (int j = 0; j < 8; j++) {
                float hy = hown[r][kbl * 8 + j];
                short hh = f2bf(hy);
                u.v[j] = pl ? f2bf(hy - bf2f(hh)) : hh;
            }
            unsigned long long* dp = (unsigned long long*)
                (hdst + (size_t)pl * 65536 + (size_t)(2 * c + kbl) * 128 + r * 8);
            __hip_atomic_store(dp,     u.qq[0], __ATOMIC_RELAXED, __HIP_MEMORY_SCOPE_AGENT);
            __hip_atomic_store(dp + 1, u.qq[1], __ATOMIC_RELAXED, __HIP_MEMORY_SCOPE_AGENT);
        }
        asm volatile("s_waitcnt vmcnt(0)" ::: "memory");
        __syncthreads();

        // ===== arrive: relaxed store to OWN flag slot (group-local consumers)
        if (tid == 0)
            __hip_atomic_store(&cnt[(t & 1) * 256 + gb * 64 + c], (unsigned)(t + 1),
                               __ATOMIC_RELAXED, __HIP_MEMORY_SCOPE_AGENT);
    }
}

extern "C" void kernel_launch(void* const* d_in, const int* in_sizes, int n_in,
                              void* d_out, int out_size, void* d_ws, size_t ws_size,
                              hipStream_t stream)
{
    const void* inputs = d_in[0];
    const void* Wx     = d_in[1];
    const void* bx     = d_in[2];
    const void* Wh     = d_in[3];
    const void* bh     = d_in[4];
    const void* Wo     = d_in[5];
    const void* bo     = d_in[6];

    const size_t HID_ELEMS = (size_t)64 * 512 * 1024;   // 33,554,432

    short* hb; unsigned* cnt; unsigned* flag;
    const bool use_ws = (d_ws != nullptr) && (ws_size >= (size_t)(4096 + 4 * 65536 * 2));
    if (use_ws) {
        cnt  = (unsigned*)d_ws;                  // 512 u32: flags[2][4][64]
        flag = cnt + 512;                        // 1 u32
        hb   = (short*)((char*)d_ws + 4096);     // 512 KiB, 16B-aligned
    } else {
        short* outh = (short*)d_out + HID_ELEMS;
        hb   = outh;
        cnt  = (unsigned*)(outh + 4 * 65536);
        flag = nullptr;
    }

    if (use_ws) detect_dtype<<<1, 64, 0, stream>>>((const unsigned short*)inputs, flag);
    init_scratch<<<1024, 256, 0, stream>>>(hb, cnt);

    gru_rec<<<NWG, 192, 0, stream>>>(inputs, Wx, bx, Wh, bh, hb, cnt, flag, d_out);

    // clock probe: ~750 us @2.4 GHz (infer from total - gru_rec - gemm); sink = dead hb
    dpm_spin<<<2048, 256, 0, stream>>>((const float*)Wx, (float*)hb, 7032);

    // out = hiddens @ Wo^T + bo : (32768 x 1024) @ (1024 x 512)
    gemm_bt<<<dim3(256, 4), 256, 0, stream>>>(d_out, Wo, bo, d_out, HID_ELEMS, flag, 32768, 512, 1024);
}